// Round 6
// baseline (319.267 us; speedup 1.0000x reference)
//
#include <hip/hip_runtime.h>
#include <hip/hip_bf16.h>

#define S_LEN 2048
#define BATCH 4
#define DMODEL 1024
#define NHEAD 16
#define HDIM 64
#define E3 3072

typedef __bf16 bf16x8 __attribute__((ext_vector_type(8)));
typedef __bf16 bf16x4 __attribute__((ext_vector_type(4)));
typedef float f32x4 __attribute__((ext_vector_type(4)));

typedef const __attribute__((address_space(1))) void gvoid;
typedef __attribute__((address_space(3))) void lvoid;

// ---------------------------------------------------------------------------
// fp32 -> bf16 elementwise cast, 8 elems/thread
// ---------------------------------------------------------------------------
__global__ void cast_f32_bf16(const float* __restrict__ src, __bf16* __restrict__ dst) {
    int i = (blockIdx.x * 256 + threadIdx.x) * 8;
    float4 a = *(const float4*)(src + i);
    float4 b = *(const float4*)(src + i + 4);
    bf16x8 v;
    v[0] = (__bf16)a.x; v[1] = (__bf16)a.y; v[2] = (__bf16)a.z; v[3] = (__bf16)a.w;
    v[4] = (__bf16)b.x; v[5] = (__bf16)b.y; v[6] = (__bf16)b.z; v[7] = (__bf16)b.w;
    *(bf16x8*)(dst + i) = v;
}

// ---------------------------------------------------------------------------
// Tiled transpose + fp32->bf16 cast: dst[c][r] = (bf16)src[r][c]
// ---------------------------------------------------------------------------
__global__ void transpose_f32_bf16(const float* __restrict__ src, __bf16* __restrict__ dst,
                                   int R, int C) {
    __shared__ float tile[32][33];
    int c0 = blockIdx.x * 32, r0 = blockIdx.y * 32;
    int tx = threadIdx.x, ty = threadIdx.y;
#pragma unroll
    for (int i = 0; i < 32; i += 8)
        tile[ty + i][tx] = src[(size_t)(r0 + ty + i) * C + c0 + tx];
    __syncthreads();
#pragma unroll
    for (int i = 0; i < 32; i += 8)
        dst[(size_t)(c0 + ty + i) * R + r0 + tx] = (__bf16)tile[tx][ty + i];
}

// ---------------------------------------------------------------------------
// Per-head V transpose: VT[b][h][hd][s] = V[b][s][h][hd]  (V = qkv slice 2D..3D)
// ---------------------------------------------------------------------------
__global__ void transpose_v(const __bf16* __restrict__ qkv, __bf16* __restrict__ vt) {
    __shared__ unsigned short tile[64][65];
    int bh = blockIdx.y;
    int s0 = blockIdx.x * 64;
    int tx = threadIdx.x & 31, ty = threadIdx.x >> 5;  // 32 x 8
    const __bf16* src = qkv + (size_t)(bh >> 4) * S_LEN * E3 + 2 * DMODEL + (bh & 15) * HDIM;
#pragma unroll
    for (int i = 0; i < 8; i++) {
        ushort2 v = *(const ushort2*)(src + (size_t)(s0 + ty + i * 8) * E3 + 2 * tx);
        tile[2 * tx][ty + i * 8] = v.x;
        tile[2 * tx + 1][ty + i * 8] = v.y;
    }
    __syncthreads();
    __bf16* dst = vt + (size_t)bh * HDIM * S_LEN + s0;
#pragma unroll
    for (int i = 0; i < 8; i++) {
        ushort2 v;
        v.x = tile[ty + i * 8][2 * tx];
        v.y = tile[ty + i * 8][2 * tx + 1];
        *(ushort2*)(dst + (size_t)(ty + i * 8) * S_LEN + 2 * tx) = v;
    }
}

// ---------------------------------------------------------------------------
// bf16 GEMM, C[r][n] = sum_k A[r][k] * BT[n][k], m97-style async staging.
// Tile 128x128, BK=32, 256 threads = 4 waves (2x2). T1 XCD-swizzled grid.
// ---------------------------------------------------------------------------
__global__ __launch_bounds__(256) void gemm_bt(
    const __bf16* __restrict__ A, const __bf16* __restrict__ BT, void* __restrict__ C,
    int K, int aSB, int aSS, int cSB, int cSS, int cF32) {
    __shared__ __bf16 lA[128 * 32];
    __shared__ __bf16 lB[128 * 32];

    const int tid = threadIdx.x;
    const int lane = tid & 63;
    const int quad = lane >> 4, l16 = lane & 15;
    const int wave = tid >> 6;
    const int wm = wave >> 1, wn = wave & 1;

    const int bid0 = blockIdx.y * gridDim.x + blockIdx.x;
    const int nwg = gridDim.x * gridDim.y;
    const int lid = (bid0 & 7) * (nwg >> 3) + (bid0 >> 3);
    const int bx = lid % gridDim.x;
    const int by = lid / gridDim.x;

    const int rm0 = by * 128;
    const int n0 = bx * 128;
    const int bb = rm0 / S_LEN;
    const int s0 = rm0 % S_LEN;

    const int lrow = lane >> 2;
    const int lch = (lane & 3) * 8;
    const int row0 = wave * 32;
    const __bf16* gA0 = A + (size_t)bb * aSB + (size_t)(s0 + row0 + lrow) * aSS + lch;
    const __bf16* gA1 = A + (size_t)bb * aSB + (size_t)(s0 + row0 + 16 + lrow) * aSS + lch;
    const __bf16* gB0 = BT + (size_t)(n0 + row0 + lrow) * K + lch;
    const __bf16* gB1 = BT + (size_t)(n0 + row0 + 16 + lrow) * K + lch;
    __bf16* ldsA0 = &lA[row0 * 32];
    __bf16* ldsA1 = &lA[(row0 + 16) * 32];
    __bf16* ldsB0 = &lB[row0 * 32];
    __bf16* ldsB1 = &lB[(row0 + 16) * 32];

    f32x4 acc[4][4];
#pragma unroll
    for (int i = 0; i < 4; i++)
#pragma unroll
        for (int j = 0; j < 4; j++) acc[i][j] = (f32x4){0.f, 0.f, 0.f, 0.f};

    for (int k0 = 0; k0 < K; k0 += 32) {
        __builtin_amdgcn_global_load_lds((gvoid*)(gA0 + k0), (lvoid*)ldsA0, 16, 0, 0);
        __builtin_amdgcn_global_load_lds((gvoid*)(gA1 + k0), (lvoid*)ldsA1, 16, 0, 0);
        __builtin_amdgcn_global_load_lds((gvoid*)(gB0 + k0), (lvoid*)ldsB0, 16, 0, 0);
        __builtin_amdgcn_global_load_lds((gvoid*)(gB1 + k0), (lvoid*)ldsB1, 16, 0, 0);
        __syncthreads();

        bf16x8 aF[4], bF[4];
#pragma unroll
        for (int i = 0; i < 4; i++) {
            aF[i] = *(const bf16x8*)&lA[(wm * 64 + i * 16 + l16) * 32 + quad * 8];
            bF[i] = *(const bf16x8*)&lB[(wn * 64 + i * 16 + l16) * 32 + quad * 8];
        }
#pragma unroll
        for (int i = 0; i < 4; i++)
#pragma unroll
            for (int j = 0; j < 4; j++)
                acc[i][j] = __builtin_amdgcn_mfma_f32_16x16x32_bf16(aF[i], bF[j], acc[i][j], 0, 0, 0);
        __syncthreads();
    }

#pragma unroll
    for (int i = 0; i < 4; i++) {
        const int rl = wm * 64 + i * 16 + quad * 4;
#pragma unroll
        for (int r = 0; r < 4; r++) {
            const size_t rowOff = (size_t)bb * cSB + (size_t)(s0 + rl + r) * cSS + n0 + wn * 64 + l16;
            if (cF32) {
                float* cRow = (float*)C + rowOff;
#pragma unroll
                for (int j = 0; j < 4; j++) cRow[j * 16] = acc[i][j][r];
            } else {
                __bf16* cRow = (__bf16*)C + rowOff;
#pragma unroll
                for (int j = 0; j < 4; j++) cRow[j * 16] = (__bf16)acc[i][j][r];
            }
        }
    }
}

// ---------------------------------------------------------------------------
// RoPE in-place on q,k slices of qkv (B,S,3D) bf16; vectorized 8 elems/thread.
// ---------------------------------------------------------------------------
__global__ void rope_kernel(__bf16* __restrict__ qkv, const float* __restrict__ cosb,
                            const float* __restrict__ sinb) {
    int idx = blockIdx.x * 256 + threadIdx.x;  // B*S*2*D/8 threads
    int t8 = idx & 7;
    int h = (idx >> 3) & 15;
    int part = (idx >> 7) & 1;
    int row = idx >> 8;  // b*S + s
    int s = row & (S_LEN - 1);
    size_t base = (size_t)row * E3 + part * DMODEL + h * HDIM + t8 * 8;
    bf16x8 v = *(const bf16x8*)(qkv + base);
    const float* cp = cosb + s * HDIM + t8 * 8;
    const float* sp = sinb + s * HDIM + t8 * 8;
    float4 c0 = *(const float4*)cp;
    float4 c1 = *(const float4*)(cp + 4);
    float4 s0 = *(const float4*)sp;
    float4 s1 = *(const float4*)(sp + 4);
    bf16x8 o;
    float x0, x1;
    x0 = (float)v[0]; x1 = (float)v[1];
    o[0] = (__bf16)(x0 * c0.x - x1 * s0.x);
    o[1] = (__bf16)(x1 * c0.y + x0 * s0.y);
    x0 = (float)v[2]; x1 = (float)v[3];
    o[2] = (__bf16)(x0 * c0.z - x1 * s0.z);
    o[3] = (__bf16)(x1 * c0.w + x0 * s0.w);
    x0 = (float)v[4]; x1 = (float)v[5];
    o[4] = (__bf16)(x0 * c1.x - x1 * s1.x);
    o[5] = (__bf16)(x1 * c1.y + x0 * s1.y);
    x0 = (float)v[6]; x1 = (float)v[7];
    o[6] = (__bf16)(x0 * c1.z - x1 * s1.z);
    o[7] = (__bf16)(x1 * c1.w + x0 * s1.w);
    *(bf16x8*)(qkv + base) = o;
}

// ---------------------------------------------------------------------------
// Flash attention, REGISTER-P, FUSED paired strips. Swapped QK^T (mfma(K,Q))
// puts a full q-row of scores in each lane; the shared key permutation
// pi(quad*8+i) = 4*quad + (i&3) + 16*(i>>2) applied to BOTH the lane-local P
// fragment and the V fragment (2x ds_read_b64) makes PV legal with no
// cross-lane P movement. This round: ONE kf/vf LDS read feeds BOTH strips'
// MFMAs (2x MFMA ILP, halved LDS reads/conflicts vs split strips).
// LDS = K+VT dbuf (37 KB) -> 4 blocks/CU. grid = (16, B*H) = 1024 blocks.
// NOTE: plain __launch_bounds__(256); (256,4) caused a 200 MB spill storm (R4).
// ---------------------------------------------------------------------------
#define VT_IDX(hd, t) ((hd) * 72 + ((hd) >> 4) * 8 + (t))

__global__ __launch_bounds__(256) void attn_kernel(const __bf16* __restrict__ qkv,
                                                   const __bf16* __restrict__ vt,
                                                   __bf16* __restrict__ ctx) {
    __shared__ __bf16 sK[2][64 * 72];        // [buf][t][hd], stride 72
    __shared__ __bf16 sVT[2][64 * 72 + 32];  // [buf][hd][t], stride 72 + skew

    const int tid = threadIdx.x, lane = tid & 63, wave = tid >> 6;
    const int quad = lane >> 4, l16 = lane & 15;

    // T1: XCD swizzle (1024 blocks; 16 consecutive lids per XCD share K/V)
    const int bid0 = blockIdx.y * 16 + blockIdx.x;
    const int lid = (bid0 & 7) * 128 + (bid0 >> 3);
    const int pair = lid & 15;  // 0..15
    const int bh = lid >> 4;
    const int b = bh >> 4, h = bh & 15;

    const int qtA = pair, qtB = 31 - pair;
    const int s0A = qtA * 64 + wave * 16;
    const int s0B = qtB * 64 + wave * 16;

    const int srow = tid >> 2;
    const int c0 = (tid & 3) * 16;

    const float qscale = 0.125f * 1.44269504f;  // 1/sqrt(64) * log2(e)
    const __bf16* kBase = qkv + (size_t)(b * S_LEN + srow) * E3 + DMODEL + h * HDIM + c0;
    const __bf16* vBase = vt + ((size_t)bh * HDIM + srow) * S_LEN + c0;

    // Q fragments (used as MFMA B-operand: B[k=hd quad*8+j][n=q l16]) pre-scaled
    const __bf16* qbA = qkv + (size_t)(b * S_LEN + s0A + l16) * E3 + h * HDIM;
    const __bf16* qbB = qkv + (size_t)(b * S_LEN + s0B + l16) * E3 + h * HDIM;
    bf16x8 qfA0 = *(const bf16x8*)(qbA + quad * 8);
    bf16x8 qfA1 = *(const bf16x8*)(qbA + 32 + quad * 8);
    bf16x8 qfB0 = *(const bf16x8*)(qbB + quad * 8);
    bf16x8 qfB1 = *(const bf16x8*)(qbB + 32 + quad * 8);
#pragma unroll
    for (int i = 0; i < 8; i++) {
        qfA0[i] = (__bf16)((float)qfA0[i] * qscale);
        qfA1[i] = (__bf16)((float)qfA1[i] * qscale);
        qfB0[i] = (__bf16)((float)qfB0[i] * qscale);
        qfB1[i] = (__bf16)((float)qfB1[i] * qscale);
    }

    f32x4 oA[4], oB[4], lacA, lacB;
#pragma unroll
    for (int j = 0; j < 4; j++) {
        oA[j] = (f32x4){0.f, 0.f, 0.f, 0.f};
        oB[j] = (f32x4){0.f, 0.f, 0.f, 0.f};
    }
    lacA = (f32x4){0.f, 0.f, 0.f, 0.f};
    lacB = (f32x4){0.f, 0.f, 0.f, 0.f};

    bf16x8 ones;
#pragma unroll
    for (int i = 0; i < 8; i++) ones[i] = (__bf16)1.0f;

    // prefetch tile 0
    const __bf16* kRow = kBase;
    const __bf16* vRow = vBase;
    bf16x8 k0 = *(const bf16x8*)kRow;
    bf16x8 k1 = *(const bf16x8*)(kRow + 8);
    bf16x8 v0 = *(const bf16x8*)vRow;
    bf16x8 v1 = *(const bf16x8*)(vRow + 8);

    const int nT = qtB + 1;
#pragma unroll 1
    for (int it = 0; it < nT; ++it) {
        const int t0 = it * 64;
        __bf16* sKc = sK[it & 1];
        __bf16* sVc = sVT[it & 1];
        *(bf16x8*)&sKc[srow * 72 + c0] = k0;
        *(bf16x8*)&sKc[srow * 72 + c0 + 8] = k1;
        *(bf16x8*)&sVc[VT_IDX(srow, c0)] = v0;
        *(bf16x8*)&sVc[VT_IDX(srow, c0 + 8)] = v1;
        __syncthreads();  // sole barrier per tile (dbuf covers the WAR side)

        if (it + 1 < nT) {
            kRow += (size_t)64 * E3;
            vRow += 64;
            k0 = *(const bf16x8*)kRow;
            k1 = *(const bf16x8*)(kRow + 8);
            v0 = *(const bf16x8*)vRow;
            v1 = *(const bf16x8*)(vRow + 8);
        }

        const bool aAct = (it <= qtA);

        // ---- fused QK^T: one kf read feeds both strips (2x MFMA ILP) ----
        f32x4 scB[4], scA[4];
        __builtin_amdgcn_s_setprio(1);
#pragma unroll
        for (int jt = 0; jt < 4; jt++) {
            bf16x8 kf0 = *(const bf16x8*)&sKc[(jt * 16 + l16) * 72 + quad * 8];
            bf16x8 kf1 = *(const bf16x8*)&sKc[(jt * 16 + l16) * 72 + 32 + quad * 8];
            f32x4 zB = (f32x4){0.f, 0.f, 0.f, 0.f};
            zB = __builtin_amdgcn_mfma_f32_16x16x32_bf16(kf0, qfB0, zB, 0, 0, 0);
            scB[jt] = __builtin_amdgcn_mfma_f32_16x16x32_bf16(kf1, qfB1, zB, 0, 0, 0);
            if (aAct) {
                f32x4 zA = (f32x4){0.f, 0.f, 0.f, 0.f};
                zA = __builtin_amdgcn_mfma_f32_16x16x32_bf16(kf0, qfA0, zA, 0, 0, 0);
                scA[jt] = __builtin_amdgcn_mfma_f32_16x16x32_bf16(kf1, qfA1, zA, 0, 0, 0);
            }
        }
        __builtin_amdgcn_s_setprio(0);

        // ---- softmax (no max subtraction) -> packed bf16 P fragments ----
        bf16x8 pfB[2], pfA[2];
        if (it == qtB) {
            const int qq = s0B + l16;
#pragma unroll
            for (int kt = 0; kt < 2; kt++)
#pragma unroll
                for (int r = 0; r < 4; r++) {
                    int tt0 = t0 + (2 * kt) * 16 + quad * 4 + r;
                    int tt1 = t0 + (2 * kt + 1) * 16 + quad * 4 + r;
                    pfB[kt][r] = (__bf16)__builtin_exp2f((tt0 > qq) ? -1e9f : scB[2 * kt][r]);
                    pfB[kt][4 + r] = (__bf16)__builtin_exp2f((tt1 > qq) ? -1e9f : scB[2 * kt + 1][r]);
                }
        } else {
#pragma unroll
            for (int kt = 0; kt < 2; kt++)
#pragma unroll
                for (int r = 0; r < 4; r++) {
                    pfB[kt][r] = (__bf16)__builtin_exp2f(scB[2 * kt][r]);
                    pfB[kt][4 + r] = (__bf16)__builtin_exp2f(scB[2 * kt + 1][r]);
                }
        }
        if (aAct) {
            if (it == qtA) {
                const int qq = s0A + l16;
#pragma unroll
                for (int kt = 0; kt < 2; kt++)
#pragma unroll
                    for (int r = 0; r < 4; r++) {
                        int tt0 = t0 + (2 * kt) * 16 + quad * 4 + r;
                        int tt1 = t0 + (2 * kt + 1) * 16 + quad * 4 + r;
                        pfA[kt][r] = (__bf16)__builtin_exp2f((tt0 > qq) ? -1e9f : scA[2 * kt][r]);
                        pfA[kt][4 + r] =
                            (__bf16)__builtin_exp2f((tt1 > qq) ? -1e9f : scA[2 * kt + 1][r]);
                    }
            } else {
#pragma unroll
                for (int kt = 0; kt < 2; kt++)
#pragma unroll
                    for (int r = 0; r < 4; r++) {
                        pfA[kt][r] = (__bf16)__builtin_exp2f(scA[2 * kt][r]);
                        pfA[kt][4 + r] = (__bf16)__builtin_exp2f(scA[2 * kt + 1][r]);
                    }
            }
        }

        // ---- fused PV + ones row-sum: one vf read feeds both strips ----
        __builtin_amdgcn_s_setprio(1);
#pragma unroll
        for (int kt = 0; kt < 2; kt++) {
#pragma unroll
            for (int jhd = 0; jhd < 4; jhd++) {
                bf16x4 vlo = *(const bf16x4*)&sVc[VT_IDX(jhd * 16 + l16, kt * 32 + quad * 4)];
                bf16x4 vhi = *(const bf16x4*)&sVc[VT_IDX(jhd * 16 + l16, kt * 32 + 16 + quad * 4)];
                bf16x8 vf = __builtin_shufflevector(vlo, vhi, 0, 1, 2, 3, 4, 5, 6, 7);
                oB[jhd] = __builtin_amdgcn_mfma_f32_16x16x32_bf16(pfB[kt], vf, oB[jhd], 0, 0, 0);
                if (aAct)
                    oA[jhd] = __builtin_amdgcn_mfma_f32_16x16x32_bf16(pfA[kt], vf, oA[jhd], 0, 0, 0);
            }
            lacB = __builtin_amdgcn_mfma_f32_16x16x32_bf16(pfB[kt], ones, lacB, 0, 0, 0);
            if (aAct) lacA = __builtin_amdgcn_mfma_f32_16x16x32_bf16(pfA[kt], ones, lacA, 0, 0, 0);
        }
        __builtin_amdgcn_s_setprio(0);
    }

    // ---- epilogues (O rows: q = s0X + quad*4 + r; cols: hd = jhd*16 + l16) ----
#pragma unroll
    for (int r = 0; r < 4; r++) {
        float inv = 1.f / lacA[r];
        size_t crow = (size_t)(b * S_LEN + s0A + quad * 4 + r) * DMODEL + h * HDIM + l16;
#pragma unroll
        for (int j = 0; j < 4; j++) ctx[crow + j * 16] = (__bf16)(oA[j][r] * inv);
    }
#pragma unroll
    for (int r = 0; r < 4; r++) {
        float inv = 1.f / lacB[r];
        size_t crow = (size_t)(b * S_LEN + s0B + quad * 4 + r) * DMODEL + h * HDIM + l16;
#pragma unroll
        for (int j = 0; j < 4; j++) ctx[crow + j * 16] = (__bf16)(oB[j][r] * inv);
    }
}

// ---------------------------------------------------------------------------
extern "C" void kernel_launch(void* const* d_in, const int* in_sizes, int n_in,
                              void* d_out, int out_size, void* d_ws, size_t ws_size,
                              hipStream_t stream) {
    const float* x = (const float*)d_in[0];      // (S,B,D) fp32
    const float* cosb = (const float*)d_in[2];   // (1,1,S,HD) fp32
    const float* sinb = (const float*)d_in[3];
    const float* Wqkv = (const float*)d_in[4];   // (D, 3D) fp32
    const float* Wout = (const float*)d_in[5];   // (D, D) fp32
    float* out = (float*)d_out;                  // (S,B,D) fp32

    char* ws = (char*)d_ws;
    __bf16* qkv = (__bf16*)ws;                                     // B*S*3D bf16 = 48 MB
    __bf16* ctx = (__bf16*)(ws + 50331648);                        // B*S*D  bf16 = 16 MB
    __bf16* WqkvT = (__bf16*)(ws + 50331648 + 16777216);           // 3D*D   bf16
    __bf16* WoutT = (__bf16*)(ws + 50331648 + 16777216 + 6291456); // D*D    bf16
    __bf16* xb = ctx;  // alias: xb dead before attn writes ctx
    __bf16* vtg = (__bf16*)d_out;  // VT scratch in d_out; dead before final GEMM

    cast_f32_bf16<<<(S_LEN * BATCH * DMODEL / 8) / 256, 256, 0, stream>>>(x, xb);
    transpose_f32_bf16<<<dim3(E3 / 32, DMODEL / 32), dim3(32, 8), 0, stream>>>(Wqkv, WqkvT, DMODEL, E3);
    transpose_f32_bf16<<<dim3(DMODEL / 32, DMODEL / 32), dim3(32, 8), 0, stream>>>(Wout, WoutT, DMODEL, DMODEL);

    // qkv = xb @ Wqkv
    gemm_bt<<<dim3(E3 / 128, (BATCH * S_LEN) / 128), 256, 0, stream>>>(
        xb, WqkvT, qkv, DMODEL,
        /*aSB=*/DMODEL, /*aSS=*/BATCH * DMODEL,
        /*cSB=*/S_LEN * E3, /*cSS=*/E3, /*cF32=*/0);

    // VT[b][h][hd][s] from V slice of qkv (V is not roped)
    transpose_v<<<dim3(S_LEN / 64, BATCH * NHEAD), 256, 0, stream>>>(qkv, vtg);

    // RoPE vectorized: 8 elems (4 pairs) per thread
    rope_kernel<<<(BATCH * S_LEN * 2 * DMODEL / 8) / 256, 256, 0, stream>>>(qkv, cosb, sinb);

    attn_kernel<<<dim3(16, BATCH * NHEAD), 256, 0, stream>>>(qkv, vtg, ctx);

    // out = ctx @ Wout (fp32 out)
    gemm_bt<<<dim3(DMODEL / 128, (BATCH * S_LEN) / 128), 256, 0, stream>>>(
        ctx, WoutT, out, DMODEL,
        /*aSB=*/S_LEN * DMODEL, /*aSS=*/DMODEL,
        /*cSB=*/DMODEL, /*cSS=*/BATCH * DMODEL, /*cF32=*/1);
}

// Round 7
// 301.886 us; speedup vs baseline: 1.0576x; 1.0576x over previous
//
#include <hip/hip_runtime.h>
#include <hip/hip_bf16.h>

#define S_LEN 2048
#define BATCH 4
#define DMODEL 1024
#define NHEAD 16
#define HDIM 64
#define E3 3072

typedef __bf16 bf16x8 __attribute__((ext_vector_type(8)));
typedef __bf16 bf16x4 __attribute__((ext_vector_type(4)));
typedef __bf16 bf16x2 __attribute__((ext_vector_type(2)));
typedef float f32x4 __attribute__((ext_vector_type(4)));

typedef const __attribute__((address_space(1))) void gvoid;
typedef __attribute__((address_space(3))) void lvoid;

// ---------------------------------------------------------------------------
// fp32 -> bf16 elementwise cast, 8 elems/thread
// ---------------------------------------------------------------------------
__global__ void cast_f32_bf16(const float* __restrict__ src, __bf16* __restrict__ dst) {
    int i = (blockIdx.x * 256 + threadIdx.x) * 8;
    float4 a = *(const float4*)(src + i);
    float4 b = *(const float4*)(src + i + 4);
    bf16x8 v;
    v[0] = (__bf16)a.x; v[1] = (__bf16)a.y; v[2] = (__bf16)a.z; v[3] = (__bf16)a.w;
    v[4] = (__bf16)b.x; v[5] = (__bf16)b.y; v[6] = (__bf16)b.z; v[7] = (__bf16)b.w;
    *(bf16x8*)(dst + i) = v;
}

// ---------------------------------------------------------------------------
// Tiled transpose + fp32->bf16 cast: dst[c][r] = (bf16)src[r][c]
// ---------------------------------------------------------------------------
__global__ void transpose_f32_bf16(const float* __restrict__ src, __bf16* __restrict__ dst,
                                   int R, int C) {
    __shared__ float tile[32][33];
    int c0 = blockIdx.x * 32, r0 = blockIdx.y * 32;
    int tx = threadIdx.x, ty = threadIdx.y;
#pragma unroll
    for (int i = 0; i < 32; i += 8)
        tile[ty + i][tx] = src[(size_t)(r0 + ty + i) * C + c0 + tx];
    __syncthreads();
#pragma unroll
    for (int i = 0; i < 32; i += 8)
        dst[(size_t)(c0 + ty + i) * R + r0 + tx] = (__bf16)tile[tx][ty + i];
}

// ---------------------------------------------------------------------------
// bf16 GEMM, C[r][n] = sum_k A[r][k] * BT[n][k], m97-style async staging.
// Tile 128x128, BK=32, 256 threads = 4 waves (2x2). T1 XCD-swizzled grid.
// mode 0 (QKV GEMM): fused epilogue —
//   cols < 2048 (q,k): apply RoPE in fp32 (partner value via ds_swizzle lane^1,
//                      cos/sin from fp32 tables), write bf16 qkv.
//   cols >= 2048 (v):  write TRANSPOSED to vtg[b*1024+vcol][s] only (qkv v-slice
//                      is never read). Replaces rope_kernel + transpose_v.
// mode 1: fp32 C (output GEMM).
// ---------------------------------------------------------------------------
__global__ __launch_bounds__(256) void gemm_bt(
    const __bf16* __restrict__ A, const __bf16* __restrict__ BT, void* __restrict__ C,
    int K, int aSB, int aSS, int cSB, int cSS, int mode,
    const float* __restrict__ cosb, const float* __restrict__ sinb,
    __bf16* __restrict__ vtg) {
    __shared__ __bf16 lA[128 * 32];
    __shared__ __bf16 lB[128 * 32];

    const int tid = threadIdx.x;
    const int lane = tid & 63;
    const int quad = lane >> 4, l16 = lane & 15;
    const int wave = tid >> 6;
    const int wm = wave >> 1, wn = wave & 1;

    const int bid0 = blockIdx.y * gridDim.x + blockIdx.x;
    const int nwg = gridDim.x * gridDim.y;
    const int lid = (bid0 & 7) * (nwg >> 3) + (bid0 >> 3);
    const int bx = lid % gridDim.x;
    const int by = lid / gridDim.x;

    const int rm0 = by * 128;
    const int n0 = bx * 128;
    const int bb = rm0 / S_LEN;
    const int s0 = rm0 % S_LEN;

    const int lrow = lane >> 2;
    const int lch = (lane & 3) * 8;
    const int row0 = wave * 32;
    const __bf16* gA0 = A + (size_t)bb * aSB + (size_t)(s0 + row0 + lrow) * aSS + lch;
    const __bf16* gA1 = A + (size_t)bb * aSB + (size_t)(s0 + row0 + 16 + lrow) * aSS + lch;
    const __bf16* gB0 = BT + (size_t)(n0 + row0 + lrow) * K + lch;
    const __bf16* gB1 = BT + (size_t)(n0 + row0 + 16 + lrow) * K + lch;
    __bf16* ldsA0 = &lA[row0 * 32];
    __bf16* ldsA1 = &lA[(row0 + 16) * 32];
    __bf16* ldsB0 = &lB[row0 * 32];
    __bf16* ldsB1 = &lB[(row0 + 16) * 32];

    f32x4 acc[4][4];
#pragma unroll
    for (int i = 0; i < 4; i++)
#pragma unroll
        for (int j = 0; j < 4; j++) acc[i][j] = (f32x4){0.f, 0.f, 0.f, 0.f};

    for (int k0 = 0; k0 < K; k0 += 32) {
        __builtin_amdgcn_global_load_lds((gvoid*)(gA0 + k0), (lvoid*)ldsA0, 16, 0, 0);
        __builtin_amdgcn_global_load_lds((gvoid*)(gA1 + k0), (lvoid*)ldsA1, 16, 0, 0);
        __builtin_amdgcn_global_load_lds((gvoid*)(gB0 + k0), (lvoid*)ldsB0, 16, 0, 0);
        __builtin_amdgcn_global_load_lds((gvoid*)(gB1 + k0), (lvoid*)ldsB1, 16, 0, 0);
        __syncthreads();

        bf16x8 aF[4], bF[4];
#pragma unroll
        for (int i = 0; i < 4; i++) {
            aF[i] = *(const bf16x8*)&lA[(wm * 64 + i * 16 + l16) * 32 + quad * 8];
            bF[i] = *(const bf16x8*)&lB[(wn * 64 + i * 16 + l16) * 32 + quad * 8];
        }
#pragma unroll
        for (int i = 0; i < 4; i++)
#pragma unroll
            for (int j = 0; j < 4; j++)
                acc[i][j] = __builtin_amdgcn_mfma_f32_16x16x32_bf16(aF[i], bF[j], acc[i][j], 0, 0, 0);
        __syncthreads();
    }

    if (mode == 0) {
        if (n0 < 2048) {
            // q/k block: RoPE in fp32, then single rounding to bf16.
            // partner value (col^1) lives in lane l16^1 -> ds_swizzle xor-1
            // (BitMode 0x041F: within-32-group lane^1; quad groups preserved).
#pragma unroll
            for (int i = 0; i < 4; i++) {
                const int rl = wm * 64 + i * 16 + quad * 4;
#pragma unroll
                for (int r = 0; r < 4; r++) {
                    const int s = s0 + rl + r;
                    const size_t rowOff = (size_t)bb * cSB + (size_t)s * cSS + n0 + wn * 64 + l16;
                    __bf16* cRow = (__bf16*)C + rowOff;
                    const float* cpr = cosb + s * HDIM;
                    const float* spr = sinb + s * HDIM;
#pragma unroll
                    for (int j = 0; j < 4; j++) {
                        float x = acc[i][j][r];
                        float y = __int_as_float(
                            __builtin_amdgcn_ds_swizzle(__float_as_int(x), 0x041F));
                        float c = cpr[j * 16 + l16];
                        float sn = spr[j * 16 + l16];
                        float out = (l16 & 1) ? fmaf(y, sn, x * c) : fmaf(-y, sn, x * c);
                        cRow[j * 16] = (__bf16)out;
                    }
                }
            }
        } else {
            // v block: write transposed to vtg[(b*1024+vcol)][s]; 4 consecutive
            // s per (i,j) -> two 4B bf16x2 stores. qkv v-slice is never read.
#pragma unroll
            for (int i = 0; i < 4; i++) {
                const int rl = wm * 64 + i * 16 + quad * 4;
#pragma unroll
                for (int j = 0; j < 4; j++) {
                    const int vcol = (n0 - 2048) + wn * 64 + j * 16 + l16;
                    const size_t vbase = ((size_t)(bb * 1024 + vcol)) * S_LEN + s0 + rl;
                    bf16x2 lo = {(__bf16)acc[i][j][0], (__bf16)acc[i][j][1]};
                    bf16x2 hi = {(__bf16)acc[i][j][2], (__bf16)acc[i][j][3]};
                    *(bf16x2*)(vtg + vbase) = lo;
                    *(bf16x2*)(vtg + vbase + 2) = hi;
                }
            }
        }
    } else {
        // fp32 C (output GEMM)
#pragma unroll
        for (int i = 0; i < 4; i++) {
            const int rl = wm * 64 + i * 16 + quad * 4;
#pragma unroll
            for (int r = 0; r < 4; r++) {
                const size_t rowOff =
                    (size_t)bb * cSB + (size_t)(s0 + rl + r) * cSS + n0 + wn * 64 + l16;
                float* cRow = (float*)C + rowOff;
#pragma unroll
                for (int j = 0; j < 4; j++) cRow[j * 16] = acc[i][j][r];
            }
        }
    }
}

// ---------------------------------------------------------------------------
// Flash attention, REGISTER-P (R5 structure, best measured: 98.2 us).
// Swapped QK^T (mfma(K,Q)) puts a full q-row of scores in each lane; the
// shared key permutation pi(quad*8+i) = 4*quad + (i&3) + 16*(i>>2), applied to
// BOTH the lane-local P fragment and the V fragment (2x ds_read_b64), makes PV
// legal with NO cross-lane P movement and NO P LDS buffer. Strips processed
// sequentially (independent chains schedule better than fused lockstep - R6).
// LDS = K+VT dbuf (37 KB) -> 4 blocks/CU. grid = (16, B*H) = 1024 blocks.
// NOTE: plain __launch_bounds__(256); (256,4) caused a 200 MB spill storm (R4).
// ---------------------------------------------------------------------------
#define VT_IDX(hd, t) ((hd) * 72 + ((hd) >> 4) * 8 + (t))

__global__ __launch_bounds__(256) void attn_kernel(const __bf16* __restrict__ qkv,
                                                   const __bf16* __restrict__ vt,
                                                   __bf16* __restrict__ ctx) {
    __shared__ __bf16 sK[2][64 * 72];        // [buf][t][hd], stride 72
    __shared__ __bf16 sVT[2][64 * 72 + 32];  // [buf][hd][t], stride 72 + skew

    const int tid = threadIdx.x, lane = tid & 63, wave = tid >> 6;
    const int quad = lane >> 4, l16 = lane & 15;

    // T1: XCD swizzle (1024 blocks; 16 consecutive lids per XCD share K/V)
    const int bid0 = blockIdx.y * 16 + blockIdx.x;
    const int lid = (bid0 & 7) * 128 + (bid0 >> 3);
    const int pair = lid & 15;  // 0..15
    const int bh = lid >> 4;
    const int b = bh >> 4, h = bh & 15;

    const int qtA = pair, qtB = 31 - pair;
    const int s0A = qtA * 64 + wave * 16;
    const int s0B = qtB * 64 + wave * 16;

    const int srow = tid >> 2;
    const int c0 = (tid & 3) * 16;

    const float qscale = 0.125f * 1.44269504f;  // 1/sqrt(64) * log2(e)
    const __bf16* kBase = qkv + (size_t)(b * S_LEN + srow) * E3 + DMODEL + h * HDIM + c0;
    const __bf16* vBase = vt + ((size_t)bh * HDIM + srow) * S_LEN + c0;

    // Q fragments (used as MFMA B-operand: B[k=hd quad*8+j][n=q l16]) pre-scaled
    const __bf16* qbA = qkv + (size_t)(b * S_LEN + s0A + l16) * E3 + h * HDIM;
    const __bf16* qbB = qkv + (size_t)(b * S_LEN + s0B + l16) * E3 + h * HDIM;
    bf16x8 qfA0 = *(const bf16x8*)(qbA + quad * 8);
    bf16x8 qfA1 = *(const bf16x8*)(qbA + 32 + quad * 8);
    bf16x8 qfB0 = *(const bf16x8*)(qbB + quad * 8);
    bf16x8 qfB1 = *(const bf16x8*)(qbB + 32 + quad * 8);
#pragma unroll
    for (int i = 0; i < 8; i++) {
        qfA0[i] = (__bf16)((float)qfA0[i] * qscale);
        qfA1[i] = (__bf16)((float)qfA1[i] * qscale);
        qfB0[i] = (__bf16)((float)qfB0[i] * qscale);
        qfB1[i] = (__bf16)((float)qfB1[i] * qscale);
    }

    f32x4 oA[4], oB[4], lacA, lacB;
#pragma unroll
    for (int j = 0; j < 4; j++) {
        oA[j] = (f32x4){0.f, 0.f, 0.f, 0.f};
        oB[j] = (f32x4){0.f, 0.f, 0.f, 0.f};
    }
    lacA = (f32x4){0.f, 0.f, 0.f, 0.f};
    lacB = (f32x4){0.f, 0.f, 0.f, 0.f};

    bf16x8 ones;
#pragma unroll
    for (int i = 0; i < 8; i++) ones[i] = (__bf16)1.0f;

    // prefetch tile 0
    const __bf16* kRow = kBase;
    const __bf16* vRow = vBase;
    bf16x8 k0 = *(const bf16x8*)kRow;
    bf16x8 k1 = *(const bf16x8*)(kRow + 8);
    bf16x8 v0 = *(const bf16x8*)vRow;
    bf16x8 v1 = *(const bf16x8*)(vRow + 8);

    const int nT = qtB + 1;
#pragma unroll 1
    for (int it = 0; it < nT; ++it) {
        const int t0 = it * 64;
        __bf16* sKc = sK[it & 1];
        __bf16* sVc = sVT[it & 1];
        *(bf16x8*)&sKc[srow * 72 + c0] = k0;
        *(bf16x8*)&sKc[srow * 72 + c0 + 8] = k1;
        *(bf16x8*)&sVc[VT_IDX(srow, c0)] = v0;
        *(bf16x8*)&sVc[VT_IDX(srow, c0 + 8)] = v1;
        __syncthreads();  // sole barrier per tile (dbuf covers the WAR side)

        if (it + 1 < nT) {
            kRow += (size_t)64 * E3;
            vRow += 64;
            k0 = *(const bf16x8*)kRow;
            k1 = *(const bf16x8*)(kRow + 8);
            v0 = *(const bf16x8*)vRow;
            v1 = *(const bf16x8*)(vRow + 8);
        }

        // ================= strip B (always active) =================
        {
            f32x4 sc[4];
            __builtin_amdgcn_s_setprio(1);
#pragma unroll
            for (int jt = 0; jt < 4; jt++) {
                bf16x8 kf0 = *(const bf16x8*)&sKc[(jt * 16 + l16) * 72 + quad * 8];
                bf16x8 kf1 = *(const bf16x8*)&sKc[(jt * 16 + l16) * 72 + 32 + quad * 8];
                f32x4 z = (f32x4){0.f, 0.f, 0.f, 0.f};
                z = __builtin_amdgcn_mfma_f32_16x16x32_bf16(kf0, qfB0, z, 0, 0, 0);
                sc[jt] = __builtin_amdgcn_mfma_f32_16x16x32_bf16(kf1, qfB1, z, 0, 0, 0);
            }
            __builtin_amdgcn_s_setprio(0);

            float p[4][4];
            if (it == qtB) {
                const int qq = s0B + l16;
#pragma unroll
                for (int jt = 0; jt < 4; jt++)
#pragma unroll
                    for (int r = 0; r < 4; r++) {
                        int tt = t0 + jt * 16 + quad * 4 + r;
                        p[jt][r] = __builtin_exp2f((tt > qq) ? -1e9f : sc[jt][r]);
                    }
            } else {
#pragma unroll
                for (int jt = 0; jt < 4; jt++)
#pragma unroll
                    for (int r = 0; r < 4; r++) p[jt][r] = __builtin_exp2f(sc[jt][r]);
            }

            __builtin_amdgcn_s_setprio(1);
#pragma unroll
            for (int kt = 0; kt < 2; kt++) {
                bf16x8 pf;
#pragma unroll
                for (int r = 0; r < 4; r++) {
                    pf[r] = (__bf16)p[2 * kt][r];
                    pf[4 + r] = (__bf16)p[2 * kt + 1][r];
                }
#pragma unroll
                for (int jhd = 0; jhd < 4; jhd++) {
                    bf16x4 vlo = *(const bf16x4*)&sVc[VT_IDX(jhd * 16 + l16, kt * 32 + quad * 4)];
                    bf16x4 vhi = *(const bf16x4*)&sVc[VT_IDX(jhd * 16 + l16, kt * 32 + 16 + quad * 4)];
                    bf16x8 vf = __builtin_shufflevector(vlo, vhi, 0, 1, 2, 3, 4, 5, 6, 7);
                    oB[jhd] = __builtin_amdgcn_mfma_f32_16x16x32_bf16(pf, vf, oB[jhd], 0, 0, 0);
                }
                lacB = __builtin_amdgcn_mfma_f32_16x16x32_bf16(pf, ones, lacB, 0, 0, 0);
            }
            __builtin_amdgcn_s_setprio(0);
        }

        // ================= strip A (causal-active prefix) =================
        if (it <= qtA) {
            f32x4 sc[4];
            __builtin_amdgcn_s_setprio(1);
#pragma unroll
            for (int jt = 0; jt < 4; jt++) {
                bf16x8 kf0 = *(const bf16x8*)&sKc[(jt * 16 + l16) * 72 + quad * 8];
                bf16x8 kf1 = *(const bf16x8*)&sKc[(jt * 16 + l16) * 72 + 32 + quad * 8];
                f32x4 z = (f32x4){0.f, 0.f, 0.f, 0.f};
                z = __builtin_amdgcn_mfma_f32_16x16x32_bf16(kf0, qfA0, z, 0, 0, 0);
                sc[jt] = __builtin_amdgcn_mfma_f32_16x16x32_bf16(kf1, qfA1, z, 0, 0, 0);
            }
            __builtin_amdgcn_s_setprio(0);

            float p[4][4];
            if (it == qtA) {
                const int qq = s0A + l16;
#pragma unroll
                for (int jt = 0; jt < 4; jt++)
#pragma unroll
                    for (int r = 0; r < 4; r++) {
                        int tt = t0 + jt * 16 + quad * 4 + r;
                        p[jt][r] = __builtin_exp2f((tt > qq) ? -1e9f : sc[jt][r]);
                    }
            } else {
#pragma unroll
                for (int jt = 0; jt < 4; jt++)
#pragma unroll
                    for (int r = 0; r < 4; r++) p[jt][r] = __builtin_exp2f(sc[jt][r]);
            }

            __builtin_amdgcn_s_setprio(1);
#pragma unroll
            for (int kt = 0; kt < 2; kt++) {
                bf16x8 pf;
#pragma unroll
                for (int r = 0; r < 4; r++) {
                    pf[r] = (__bf16)p[2 * kt][r];
                    pf[4 + r] = (__bf16)p[2 * kt + 1][r];
                }
#pragma unroll
                for (int jhd = 0; jhd < 4; jhd++) {
                    bf16x4 vlo = *(const bf16x4*)&sVc[VT_IDX(jhd * 16 + l16, kt * 32 + quad * 4)];
                    bf16x4 vhi = *(const bf16x4*)&sVc[VT_IDX(jhd * 16 + l16, kt * 32 + 16 + quad * 4)];
                    bf16x8 vf = __builtin_shufflevector(vlo, vhi, 0, 1, 2, 3, 4, 5, 6, 7);
                    oA[jhd] = __builtin_amdgcn_mfma_f32_16x16x32_bf16(pf, vf, oA[jhd], 0, 0, 0);
                }
                lacA = __builtin_amdgcn_mfma_f32_16x16x32_bf16(pf, ones, lacA, 0, 0, 0);
            }
            __builtin_amdgcn_s_setprio(0);
        }
    }

    // ---- epilogues (O rows: q = s0X + quad*4 + r; cols: hd = jhd*16 + l16) ----
#pragma unroll
    for (int r = 0; r < 4; r++) {
        float inv = 1.f / lacA[r];
        size_t crow = (size_t)(b * S_LEN + s0A + quad * 4 + r) * DMODEL + h * HDIM + l16;
#pragma unroll
        for (int j = 0; j < 4; j++) ctx[crow + j * 16] = (__bf16)(oA[j][r] * inv);
    }
#pragma unroll
    for (int r = 0; r < 4; r++) {
        float inv = 1.f / lacB[r];
        size_t crow = (size_t)(b * S_LEN + s0B + quad * 4 + r) * DMODEL + h * HDIM + l16;
#pragma unroll
        for (int j = 0; j < 4; j++) ctx[crow + j * 16] = (__bf16)(oB[j][r] * inv);
    }
}

// ---------------------------------------------------------------------------
extern "C" void kernel_launch(void* const* d_in, const int* in_sizes, int n_in,
                              void* d_out, int out_size, void* d_ws, size_t ws_size,
                              hipStream_t stream) {
    const float* x = (const float*)d_in[0];      // (S,B,D) fp32
    const float* cosb = (const float*)d_in[2];   // (1,1,S,HD) fp32
    const float* sinb = (const float*)d_in[3];
    const float* Wqkv = (const float*)d_in[4];   // (D, 3D) fp32
    const float* Wout = (const float*)d_in[5];   // (D, D) fp32
    float* out = (float*)d_out;                  // (S,B,D) fp32

    char* ws = (char*)d_ws;
    __bf16* qkv = (__bf16*)ws;                                     // B*S*3D bf16 = 48 MB
    __bf16* ctx = (__bf16*)(ws + 50331648);                        // B*S*D  bf16 = 16 MB
    __bf16* WqkvT = (__bf16*)(ws + 50331648 + 16777216);           // 3D*D   bf16
    __bf16* WoutT = (__bf16*)(ws + 50331648 + 16777216 + 6291456); // D*D    bf16
    __bf16* xb = ctx;  // alias: xb dead before attn writes ctx
    __bf16* vtg = (__bf16*)d_out;  // VT scratch in d_out; dead before final GEMM

    cast_f32_bf16<<<(S_LEN * BATCH * DMODEL / 8) / 256, 256, 0, stream>>>(x, xb);
    transpose_f32_bf16<<<dim3(E3 / 32, DMODEL / 32), dim3(32, 8), 0, stream>>>(Wqkv, WqkvT, DMODEL, E3);
    transpose_f32_bf16<<<dim3(DMODEL / 32, DMODEL / 32), dim3(32, 8), 0, stream>>>(Wout, WoutT, DMODEL, DMODEL);

    // qkv = xb @ Wqkv, with fused RoPE (q,k) and fused V-transpose -> vtg
    gemm_bt<<<dim3(E3 / 128, (BATCH * S_LEN) / 128), 256, 0, stream>>>(
        xb, WqkvT, qkv, DMODEL,
        /*aSB=*/DMODEL, /*aSS=*/BATCH * DMODEL,
        /*cSB=*/S_LEN * E3, /*cSS=*/E3, /*mode=*/0, cosb, sinb, vtg);

    attn_kernel<<<dim3(16, BATCH * NHEAD), 256, 0, stream>>>(qkv, vtg, ctx);

    // out = ctx @ Wout (fp32 out)
    gemm_bt<<<dim3(DMODEL / 128, (BATCH * S_LEN) / 128), 256, 0, stream>>>(
        ctx, WoutT, out, DMODEL,
        /*aSB=*/S_LEN * DMODEL, /*aSS=*/DMODEL,
        /*cSB=*/DMODEL, /*cSS=*/BATCH * DMODEL, /*mode=*/1, nullptr, nullptr, nullptr);
}